// Round 5
// baseline (111.544 us; speedup 1.0000x reference)
//
#include <hip/hip_runtime.h>
#include <stdint.h>

#define BB 8
#define LLEN 16384
#define CC 64
#define TOUT 8186
#define TILE_T 32
#define NROWS 76            // 2*TILE_T + 12 halo rows
#define SXS 68              // fp32 words/row (272B)
#define YNS 66              // fp32 words/row
#define YNBS 76             // shorts/row

typedef __attribute__((ext_vector_type(8))) short short8;
typedef __attribute__((ext_vector_type(4))) float float4v;
typedef __attribute__((ext_vector_type(4))) unsigned short ushort4v;

__device__ inline unsigned short f2bf(float f) {
  union { float f; uint32_t u; } v; v.f = f;
  uint32_t r = v.u + 0x7fffu + ((v.u >> 16) & 1u);
  return (unsigned short)(r >> 16);
}
__device__ inline float rcp_fast(float x) {
  float r; asm("v_rcp_f32 %0, %1" : "=v"(r) : "v"(x)); return r;
}
__device__ inline float exp2_fast(float x) {
  float r; asm("v_exp_f32 %0, %1" : "=v"(r) : "v"(x)); return r;
}
// exp-form tanh (R6/R12-validated, absmax 0.03125): 5 inst/gate
// (mul, v_exp, add, v_rcp, fma); saturates exactly at +/-1.
__device__ inline float tanh_fast(float a) {
  float e = exp2_fast(a * 2.885390082f);        // e^{2a} = 2^{2a*log2(e)}
  return __builtin_fmaf(-2.0f, rcp_fast(e + 1.0f), 1.0f);
}

// Pack fp32 weights (C,C,K) -> bf16 MFMA B-frags (n = kk*64+d, d = 16*dq+l15),
// and fp32 conv_kernel (C,C) -> bf16 B-frags (n = o, k = c).
// NOTE (R13): remapping d -> 4*l15+dq (for contiguous sx2 reads) failed
// correctness (absmax 0.39) — root cause not found; keep this verified layout.
__global__ void prep_frags(const float* __restrict__ weights,
                           const float* __restrict__ ck,
                           unsigned short* __restrict__ wfrag,
                           unsigned short* __restrict__ ckfrag)
{
  int bid = blockIdx.x, tid = threadIdx.x;
  if (bid < 56) {                       // 28 ntiles x 2 khalves
    int nt = bid >> 1, kh = bid & 1;
    for (int e = tid; e < 512; e += 256) {
      int ln = e >> 3, j = e & 7;
      int kk = nt >> 2;                 // nt = kk*4 + dq
      int d  = (nt & 3) * 16 + (ln & 15);
      int cp = kh * 32 + (ln >> 4) * 8 + j;
      wfrag[(bid * 64 + ln) * 8 + j] = f2bf(weights[d * 448 + cp * 7 + kk]);
    }
  } else {                              // conv kernel: 4 ntiles x 2 khalves
    int bb2 = bid - 56;
    int nt = bb2 >> 1, kh = bb2 & 1;
    for (int e = tid; e < 512; e += 256) {
      int ln = e >> 3, j = e & 7;
      int oo = nt * 16 + (ln & 15);
      int c2 = kh * 32 + (ln >> 4) * 8 + j;
      ckfrag[(bb2 * 64 + ln) * 8 + j] = f2bf(ck[c2 * 64 + oo]);
    }
  }
}

// R18: occupancy push. R12/R17 iso-perf at 5 blocks/CU with totally
// different B-paths => pipes not saturated; kernel is latency-bound
// (issue-work ~13us/SIMD vs 34us measured). Lever = TLP:
//  - sxg ELIMINATED (9,216B): a0/a1 built from sx2 via 16 scattered
//    ds_read_u32 + f2bf per thread (once) — bit-identical bf16 (sxg held
//    f2bf of the same floats). Phase-1 bf16 side-writes and barrier B2 gone.
//  - ynf/ynb relocated as post-B3 overlays of dead sx2 (13,312 <= 20,672).
// LDS 29,888 -> 20,672 B => 7 blocks/CU LDS-wise; launch_bounds(256,6)
// caps VGPR at 85 (R12 ran ~64; no R15-style spill) -> 6-7 blocks/CU.
// kk-loop is exact R12 (global B-frags, rolled). Arithmetic bit-identical.
__global__ __launch_bounds__(256, 6)
void convblock_main(const float* __restrict__ x,
                    const unsigned short* __restrict__ wfrag,
                    const unsigned short* __restrict__ ckfrag,
                    const float* __restrict__ ln_scale,
                    const float* __restrict__ ln_bias,
                    const float* __restrict__ conv_bias,
                    const float* __restrict__ prelu_slope,
                    float* __restrict__ out)
{
  __shared__ __align__(16) char smem[20672];
  float*          sx2 = (float*)smem;                    // [0, 20672), dead after B3
  unsigned short* ynb = (unsigned short*)smem;           // overlay after B3 (4864 B)
  float*          ynf = (float*)(smem + 4864);           // overlay after B3 (8448 B)

  const int tid  = threadIdx.x;
  const int b    = blockIdx.x >> 8;
  const int t0   = (blockIdx.x & 255) * TILE_T;
  const int lane = tid & 63;
  const int w    = tid >> 6;
  const int l15  = tid & 15;
  const int q    = (tid >> 4) & 3;

  // ---- phase 1: stage x slab rows 2t0..2t0+75, float4 loads ----
  {
    const float* xb = x + (size_t)b * ((size_t)LLEN * CC);
    #pragma unroll
    for (int i = 0; i < 5; ++i) {
      int idx = tid + i * 256;                  // [0, 1216) float4s
      if (idx < NROWS * 16) {
        int row = idx >> 4, f4 = idx & 15;
        int rowg = 2 * t0 + row;
        if (rowg > LLEN - 1) rowg = LLEN - 1;   // only feeds t >= TOUT (never stored)
        float4v v = *(const float4v*)(xb + (size_t)rowg * CC + f4 * 4);
        int base = row * SXS + 16 * (f4 & 3) + (f4 >> 2);  // swizzle word(c)=16*((c>>2)&3)+(c>>4)+4*(c&3)
        sx2[base + 0]  = v[0];
        sx2[base + 4]  = v[1];
        sx2[base + 8]  = v[2];
        sx2[base + 12] = v[3];
      }
    }
  }
  __syncthreads();                              // B1

  // ---- build A-frags from sx2 (bit-identical to old sxg path) ----
  // lane (q,l15) holds row 12+16w+l15, channels q*8+j (a0) / 32+q*8+j (a1).
  short8 a0, a1;
  {
    const int rowoff = (12 + 16 * w + l15) * SXS;
    #pragma unroll
    for (int j = 0; j < 8; ++j) {
      int c0 = q * 8 + j;
      int w0 = 16 * ((c0 >> 2) & 3) + (c0 >> 4) + 4 * (c0 & 3);
      a0[j] = (short)f2bf(sx2[rowoff + w0]);
      int c1 = 32 + q * 8 + j;
      int w1 = 16 * ((c1 >> 2) & 3) + (c1 >> 4) + 4 * (c1 & 3);
      a1[j] = (short)f2bf(sx2[rowoff + w1]);
    }
  }

  // ---- phase 2+3 fused: ROLLED per-kk loop: MFMA -> tanh -> y ----
  float y[2][4];
  #pragma unroll
  for (int dlt = 0; dlt < 2; ++dlt)
    #pragma unroll
    for (int dq = 0; dq < 4; ++dq) y[dlt][dq] = 0.f;

  const float4v zacc = (float4v){0.f, 0.f, 0.f, 0.f};
  const int dtbase = 8 * w + 2 * q;             // local t = dtbase + dlt
  const unsigned short* wp = wfrag + lane * 8;  // += 4096 shorts per kk
  #pragma unroll 1
  for (int kk = 0; kk < 7; ++kk) {
    float4v acc[4];
    #pragma unroll
    for (int dq = 0; dq < 4; ++dq) {
      short8 b0 = *(const short8*)(wp + dq * 1024);
      short8 b1 = *(const short8*)(wp + dq * 1024 + 512);
      float4v a = __builtin_amdgcn_mfma_f32_16x16x32_bf16(a0, b0, zacc, 0, 0, 0);
      acc[dq] = __builtin_amdgcn_mfma_f32_16x16x32_bf16(a1, b1, a, 0, 0, 0);
    }
    #pragma unroll
    for (int dlt = 0; dlt < 2; ++dlt) {
      int rowe = 2 * (dtbase + dlt) + 2 * kk;
      float4v xe = *(const float4v*)&sx2[rowe * SXS + l15 * 4];
      float4v xo = *(const float4v*)&sx2[(rowe + 1) * SXS + l15 * 4];
      #pragma unroll
      for (int dq = 0; dq < 4; ++dq) {
        float ge = tanh_fast(acc[dq][2 * dlt + 0]);
        float go = tanh_fast(acc[dq][2 * dlt + 1]);
        y[dlt][dq] += xe[dq] * ge + xo[dq] * go;
      }
    }
    wp += 4096;
  }
  // residual x[12+2t] (even element of the kk=6 row)
  #pragma unroll
  for (int dlt = 0; dlt < 2; ++dlt) {
    int rowe = 2 * (dtbase + dlt) + 12;
    float4v xe = *(const float4v*)&sx2[rowe * SXS + l15 * 4];
    #pragma unroll
    for (int dq = 0; dq < 4; ++dq) y[dlt][dq] += xe[dq];
  }

  // ---- LayerNorm (registers + 16-lane shuffle) ----
  float lnS[4], lnB[4];
  #pragma unroll
  for (int dq = 0; dq < 4; ++dq) {
    lnS[dq] = ln_scale[16 * dq + l15];
    lnB[dq] = ln_bias[16 * dq + l15];
  }
  float ynr[2][4];
  #pragma unroll
  for (int dlt = 0; dlt < 2; ++dlt) {
    float s1 = y[dlt][0] + y[dlt][1] + y[dlt][2] + y[dlt][3];
    float s2 = y[dlt][0]*y[dlt][0] + y[dlt][1]*y[dlt][1]
             + y[dlt][2]*y[dlt][2] + y[dlt][3]*y[dlt][3];
    #pragma unroll
    for (int m = 1; m < 16; m <<= 1) {
      s1 += __shfl_xor(s1, m, 64);
      s2 += __shfl_xor(s2, m, 64);
    }
    float mu   = s1 * (1.0f / 64.0f);
    float var  = s2 * (1.0f / 64.0f) - mu * mu;
    float rstd = rsqrtf(var + 1e-6f);
    #pragma unroll
    for (int dq = 0; dq < 4; ++dq)
      ynr[dlt][dq] = (y[dlt][dq] - mu) * rstd * lnS[dq] + lnB[dq];
  }
  __syncthreads();                              // B3: ALL sx2 reads done -> overlays live

  // ---- write ynf (fp32) + ynb (bf16 A-frags), both sx2 overlays ----
  #pragma unroll
  for (int dlt = 0; dlt < 2; ++dlt) {
    int dt = dtbase + dlt;
    #pragma unroll
    for (int dq = 0; dq < 4; ++dq) {
      ynf[dt * YNS + 16 * dq + l15] = ynr[dlt][dq];
      ynb[dt * YNBS + 16 * dq + l15] = f2bf(ynr[dlt][dq]);
    }
  }
  __syncthreads();                              // B4

  // ---- phase 4: z = yn@ck + cb via MFMA, PReLU, out = yn + z ----
  const float sl = prelu_slope[0];
  const int   o  = 16 * w + l15;                // wave w owns o-tile w
  const float cb = conv_bias[o];
  short8 bf0 = *(const short8*)&ckfrag[((w * 2 + 0) * 64 + lane) * 8];
  short8 bf1 = *(const short8*)&ckfrag[((w * 2 + 1) * 64 + lane) * 8];
  #pragma unroll
  for (int mt = 0; mt < 2; ++mt) {
    short8 af0 = *(const short8*)&ynb[(mt * 16 + l15) * YNBS + q * 8];
    short8 af1 = *(const short8*)&ynb[(mt * 16 + l15) * YNBS + 32 + q * 8];
    float4v zc = __builtin_amdgcn_mfma_f32_16x16x32_bf16(af0, bf0, zacc, 0, 0, 0);
    zc = __builtin_amdgcn_mfma_f32_16x16x32_bf16(af1, bf1, zc, 0, 0, 0);
    #pragma unroll
    for (int r = 0; r < 4; ++r) {
      int t  = mt * 16 + 4 * q + r;
      int tg = t0 + t;
      if (tg < TOUT) {
        float z = zc[r] + cb;
        z = (z >= 0.f) ? z : sl * z;
        out[((size_t)b * TOUT + tg) * CC + o] = ynf[t * YNS + o] + z;
      }
    }
  }
}

extern "C" void kernel_launch(void* const* d_in, const int* in_sizes, int n_in,
                              void* d_out, int out_size, void* d_ws, size_t ws_size,
                              hipStream_t stream)
{
  const float* x        = (const float*)d_in[0];
  const float* weights  = (const float*)d_in[1];
  const float* ln_scale = (const float*)d_in[2];
  const float* ln_bias  = (const float*)d_in[3];
  const float* ck       = (const float*)d_in[4];
  const float* cb       = (const float*)d_in[5];
  const float* slope    = (const float*)d_in[6];
  unsigned short* wfrag  = (unsigned short*)d_ws;                  // 57344 B
  unsigned short* ckfrag = (unsigned short*)((char*)d_ws + 57344); // 8192 B

  prep_frags<<<64, 256, 0, stream>>>(weights, ck, wfrag, ckfrag);
  convblock_main<<<BB * 256, 256, 0, stream>>>(x, wfrag, ckfrag, ln_scale,
                                               ln_bias, cb, slope, (float*)d_out);
}